// Round 1
// baseline (458.288 us; speedup 1.0000x reference)
//
#include <hip/hip_runtime.h>
#include <stdint.h>

typedef __attribute__((ext_vector_type(8))) short bf16x8;
typedef __attribute__((ext_vector_type(4))) float f32x4;

#define GLB(p) ((__attribute__((address_space(1))) void*)(p))
#define LDSP(p) ((__attribute__((address_space(3))) void*)(p))

__device__ __forceinline__ unsigned short f2bf(float f) {
  union { float f; unsigned u; } v; v.f = f;
  unsigned r = v.u + 0x7fffu + ((v.u >> 16) & 1u);
  return (unsigned short)(r >> 16);
}

// ---- x (fp32, 6291456) -> bf16 ----
__global__ __launch_bounds__(256) void k_convert_x(const float* __restrict__ x,
                                                   unsigned short* __restrict__ X) {
  int i = blockIdx.x * 256 + threadIdx.x;
  float4 v = ((const float4*)x)[i];
  ushort4 o;
  o.x = f2bf(v.x); o.y = f2bf(v.y); o.z = f2bf(v.z); o.w = f2bf(v.w);
  ((ushort4*)X)[i] = o;
}

// ---- transpose 768x768 fp32 -> bf16, dst[c][r] = src[r][c] ----
__global__ __launch_bounds__(256) void k_transpose_w(const float* __restrict__ src,
                                                     unsigned short* __restrict__ dst) {
  __shared__ float t[32][33];
  int tx = threadIdx.x & 31, ty = threadIdx.x >> 5;
  int c0 = blockIdx.x * 32, r0 = blockIdx.y * 32;
  #pragma unroll
  for (int i = 0; i < 4; ++i)
    t[ty + i * 8][tx] = src[(size_t)(r0 + ty + i * 8) * 768 + c0 + tx];
  __syncthreads();
  #pragma unroll
  for (int i = 0; i < 4; ++i)
    dst[(size_t)(c0 + ty + i * 8) * 768 + r0 + tx] = f2bf(t[tx][ty + i * 8]);
}

// ---- transpose V [192][512][64] -> VT [192][64][512] (bf16) ----
__global__ __launch_bounds__(256) void k_transpose_v(const unsigned short* __restrict__ V,
                                                     unsigned short* __restrict__ VT) {
  __shared__ unsigned short t[32][33];
  int tx = threadIdx.x & 31, ty = threadIdx.x >> 5;
  int c0 = blockIdx.x * 32;   // d
  int r0 = blockIdx.y * 32;   // n
  int bh = blockIdx.z;
  const unsigned short* src = V + (size_t)bh * 512 * 64;
  unsigned short* dst = VT + (size_t)bh * 64 * 512;
  #pragma unroll
  for (int i = 0; i < 4; ++i)
    t[ty + i * 8][tx] = src[(r0 + ty + i * 8) * 64 + c0 + tx];
  __syncthreads();
  #pragma unroll
  for (int i = 0; i < 4; ++i)
    dst[(c0 + ty + i * 8) * 512 + r0 + tx] = t[tx][ty + i * 8];
}

// ---- GEMM core: C(128x128 tile) = A(Mx768) * Bt(Nx768)^T, bf16 MFMA ----
// EPI 0: QKV routing epilogue (bias add, scatter to Q/K/V per-head buffers)
// EPI 1: fp32 output epilogue (bias add, row-major C)
template <int EPI>
__global__ __launch_bounds__(256) void k_gemm(
    const unsigned short* __restrict__ A, const unsigned short* __restrict__ Bt,
    const float* __restrict__ b0, const float* __restrict__ b1, const float* __restrict__ b2,
    unsigned short* __restrict__ Qo, unsigned short* __restrict__ Ko,
    unsigned short* __restrict__ Vo, float* __restrict__ Co) {
  __shared__ unsigned short sA[128 * 32];
  __shared__ unsigned short sB[128 * 32];
  const int tid = threadIdx.x, lane = tid & 63, wid = tid >> 6;
  const int wr = wid >> 1, wc = wid & 1;
  const int m0 = blockIdx.y * 128, n0 = blockIdx.x * 128;
  const int lrow = lane >> 2, lkoff = (lane & 3) * 8;
  const int fr = lane & 15, fg = lane >> 4;
  f32x4 acc[4][4] = {};

  for (int k0 = 0; k0 < 768; k0 += 32) {
    #pragma unroll
    for (int it = 0; it < 2; ++it) {
      int rb = it * 64 + wid * 16;
      __builtin_amdgcn_global_load_lds(GLB(A + (size_t)(m0 + rb + lrow) * 768 + k0 + lkoff),
                                       LDSP(sA + rb * 32), 16, 0, 0);
      __builtin_amdgcn_global_load_lds(GLB(Bt + (size_t)(n0 + rb + lrow) * 768 + k0 + lkoff),
                                       LDSP(sB + rb * 32), 16, 0, 0);
    }
    __syncthreads();
    bf16x8 af[4], bw[4];
    #pragma unroll
    for (int f = 0; f < 4; ++f) {
      af[f] = *(const bf16x8*)&sA[(wr * 64 + f * 16 + fr) * 32 + fg * 8];
      bw[f] = *(const bf16x8*)&sB[(wc * 64 + f * 16 + fr) * 32 + fg * 8];
    }
    #pragma unroll
    for (int i = 0; i < 4; ++i)
      #pragma unroll
      for (int j = 0; j < 4; ++j)
        acc[i][j] = __builtin_amdgcn_mfma_f32_16x16x32_bf16(af[i], bw[j], acc[i][j], 0, 0, 0);
    __syncthreads();
  }

  if (EPI == 0) {
    #pragma unroll
    for (int fm = 0; fm < 4; ++fm) {
      int row0 = m0 + wr * 64 + fm * 16;
      int nseq = row0 >> 4;  // B=16: row = n*16 + b, frag spans one n, 16 b's
      #pragma unroll
      for (int fn = 0; fn < 4; ++fn) {
        int col = n0 + wc * 64 + fn * 16 + fr;  // 0..2303
        int sel = (col >= 1536) ? 2 : (col >= 768) ? 1 : 0;
        int jj = col - sel * 768;
        int h = jj >> 6, d = jj & 63;
        const float* bp = (sel == 0) ? b0 : (sel == 1) ? b1 : b2;
        float bias = bp[jj];
        unsigned short* dst = (sel == 0) ? Qo : (sel == 1) ? Ko : Vo;
        #pragma unroll
        for (int r = 0; r < 4; ++r) {
          int bb = fg * 4 + r;
          dst[(((size_t)bb * 12 + h) * 512 + nseq) * 64 + d] = f2bf(acc[fm][fn][r] + bias);
        }
      }
    }
  } else {
    #pragma unroll
    for (int fm = 0; fm < 4; ++fm) {
      int row0 = m0 + wr * 64 + fm * 16;
      #pragma unroll
      for (int fn = 0; fn < 4; ++fn) {
        int col = n0 + wc * 64 + fn * 16 + fr;
        float bias = b0[col];
        #pragma unroll
        for (int r = 0; r < 4; ++r)
          Co[(size_t)(row0 + fg * 4 + r) * 768 + col] = acc[fm][fn][r] + bias;
      }
    }
  }
}

// ---- attention: 1 block = (bh, 64 q rows), 4 waves x 16 rows ----
__global__ __launch_bounds__(256) void k_attn(
    const unsigned short* __restrict__ Q, const unsigned short* __restrict__ K,
    const unsigned short* __restrict__ VT, const float* __restrict__ bias,
    const unsigned char* __restrict__ mask, unsigned short* __restrict__ O) {
  __shared__ unsigned short P[4][16 * 512];  // 64 KB, per-wave P strip
  const int tid = threadIdx.x, lane = tid & 63, wid = tid >> 6;
  const int bh = blockIdx.x >> 3, qt = blockIdx.x & 7;
  const int b = bh / 12, h = bh - b * 12;
  const int q0 = qt * 64 + wid * 16;
  const int fr = lane & 15, fg = lane >> 4;
  const unsigned short* Qb = Q + (size_t)bh * 512 * 64;
  const unsigned short* Kb = K + (size_t)bh * 512 * 64;
  const unsigned short* Vb = VT + (size_t)bh * 64 * 512;
  const float* Bb = bias + ((size_t)bh * 512 + q0) * 512;
  const unsigned char* mb = mask + b * 512;

  bf16x8 aq0 = *(const bf16x8*)&Qb[(q0 + fr) * 64 + fg * 8];
  bf16x8 aq1 = *(const bf16x8*)&Qb[(q0 + fr) * 64 + fg * 8 + 32];

  float s[32][4];
  #pragma unroll
  for (int t = 0; t < 32; ++t) {
    bf16x8 kb0 = *(const bf16x8*)&Kb[(t * 16 + fr) * 64 + fg * 8];
    bf16x8 kb1 = *(const bf16x8*)&Kb[(t * 16 + fr) * 64 + fg * 8 + 32];
    f32x4 a = {};
    a = __builtin_amdgcn_mfma_f32_16x16x32_bf16(aq0, kb0, a, 0, 0, 0);
    a = __builtin_amdgcn_mfma_f32_16x16x32_bf16(aq1, kb1, a, 0, 0, 0);
    int col = t * 16 + fr;
    float madd = mb[col] ? -1e30f : 0.0f;
    #pragma unroll
    for (int r = 0; r < 4; ++r)
      s[t][r] = a[r] * 0.125f + Bb[(fg * 4 + r) * 512 + col] + madd;
  }

  unsigned short* Pw = &P[wid][0];
  #pragma unroll
  for (int r = 0; r < 4; ++r) {
    float m = s[0][r];
    #pragma unroll
    for (int t = 1; t < 32; ++t) m = fmaxf(m, s[t][r]);
    #pragma unroll
    for (int o = 1; o < 16; o <<= 1) m = fmaxf(m, __shfl_xor(m, o, 16));
    float l = 0.0f;
    #pragma unroll
    for (int t = 0; t < 32; ++t) { float p = __expf(s[t][r] - m); s[t][r] = p; l += p; }
    #pragma unroll
    for (int o = 1; o < 16; o <<= 1) l += __shfl_xor(l, o, 16);
    float inv = 1.0f / l;
    int row = fg * 4 + r, swz = (row & 7) << 4;
    #pragma unroll
    for (int t = 0; t < 32; ++t) {
      int cb = (t * 16 + fr) * 2;
      *(unsigned short*)((char*)Pw + row * 1024 + (cb ^ swz)) = f2bf(s[t][r] * inv);
    }
  }
  __syncthreads();

  f32x4 o4[4] = {};
  {
    int row = fr, swz = (row & 7) << 4;
    #pragma unroll
    for (int kt = 0; kt < 16; ++kt) {
      bf16x8 pa = *(const bf16x8*)((char*)Pw + row * 1024 + ((fg * 16 + kt * 64) ^ swz));
      #pragma unroll
      for (int dt = 0; dt < 4; ++dt) {
        bf16x8 vb = *(const bf16x8*)&Vb[(size_t)(dt * 16 + fr) * 512 + kt * 32 + fg * 8];
        o4[dt] = __builtin_amdgcn_mfma_f32_16x16x32_bf16(pa, vb, o4[dt], 0, 0, 0);
      }
    }
  }
  #pragma unroll
  for (int dt = 0; dt < 4; ++dt)
    #pragma unroll
    for (int r = 0; r < 4; ++r)
      O[(size_t)((q0 + fg * 4 + r) * 16 + b) * 768 + h * 64 + dt * 16 + fr] = f2bf(o4[dt][r]);
}

extern "C" void kernel_launch(void* const* d_in, const int* in_sizes, int n_in,
                              void* d_out, int out_size, void* d_ws, size_t ws_size,
                              hipStream_t stream) {
  const float* x = (const float*)d_in[0];
  const float* ab = (const float*)d_in[1];
  const unsigned char* mask = (const unsigned char*)d_in[2];
  const float* Wq = (const float*)d_in[3];
  const float* bq = (const float*)d_in[4];
  const float* Wk = (const float*)d_in[5];
  const float* bk = (const float*)d_in[6];
  const float* Wv = (const float*)d_in[7];
  const float* bv = (const float*)d_in[8];
  const float* Wo = (const float*)d_in[9];
  const float* bo = (const float*)d_in[10];
  float* out = (float*)d_out;

  char* w = (char*)d_ws;
  unsigned short* X   = (unsigned short*)(w);              // 12582912 B ; reused as O
  unsigned short* WTq = (unsigned short*)(w + 12582912);   // 3538944 B (2304x768)
  unsigned short* WoT = (unsigned short*)(w + 16121856);   // 1179648 B
  unsigned short* Qb  = (unsigned short*)(w + 17301504);   // 12582912 B
  unsigned short* Kb  = (unsigned short*)(w + 29884416);   // 12582912 B
  unsigned short* Vn  = (unsigned short*)(w + 42467328);   // 12582912 B
  unsigned short* VT  = (unsigned short*)(w + 55050240);   // 12582912 B -> end 67633152
  unsigned short* O   = X;  // x dead after QKV GEMM

  k_convert_x<<<6144, 256, 0, stream>>>(x, X);
  dim3 tg(24, 24);
  k_transpose_w<<<tg, 256, 0, stream>>>(Wq, WTq);
  k_transpose_w<<<tg, 256, 0, stream>>>(Wk, WTq + 768 * 768);
  k_transpose_w<<<tg, 256, 0, stream>>>(Wv, WTq + 2 * 768 * 768);
  k_transpose_w<<<tg, 256, 0, stream>>>(Wo, WoT);
  k_gemm<0><<<dim3(18, 64), 256, 0, stream>>>(X, WTq, bq, bk, bv, Qb, Kb, Vn, nullptr);
  k_transpose_v<<<dim3(2, 16, 192), 256, 0, stream>>>(Vn, VT);
  k_attn<<<1536, 256, 0, stream>>>(Qb, Kb, VT, ab, mask, O);
  k_gemm<1><<<dim3(6, 64), 256, 0, stream>>>(O, WoT, bo, nullptr, nullptr, nullptr, nullptr, nullptr, out);
}